// Round 1
// baseline (98.857 us; speedup 1.0000x reference)
//
#include <hip/hip_runtime.h>
#include <hip/hip_bf16.h>

// dist[n][m] = sum_d (x[n][d]-y[m][d])^2 = |x_n|^2 + |y_m|^2 - 2 x_n.y_m
// N=M=8192, D=128, f32 in/out. Cross term via bf16 MFMA (error ~0.1 << thr 10),
// row norms in exact f32. HBM-write-bound: 256 MiB output => ~42us floor.

typedef __attribute__((ext_vector_type(8))) short short8;
typedef __attribute__((ext_vector_type(4))) float f32x4;

#define NROW 8192
#define NCOL 8192
#define DIM  128
#define BM   128
#define BN   128

__device__ __forceinline__ short f2bf(float f) {
    // round-to-nearest-even f32 -> bf16 (inputs are finite normals)
    unsigned u = __builtin_bit_cast(unsigned, f);
    unsigned r = u + 0x7FFFu + ((u >> 16) & 1u);
    return (short)(r >> 16);
}

__global__ __launch_bounds__(256, 2)
void dist_kernel(const float* __restrict__ X, const float* __restrict__ Y,
                 float* __restrict__ out)
{
    // bf16 tiles, row-major [128 rows][128 k], 256B row stride, XOR-swizzled:
    // stored byte col = logical byte col ^ ((row&7)<<4)  (involution, 16B granular)
    __shared__ unsigned short As[BM * DIM];
    __shared__ unsigned short Bs[BN * DIM];
    __shared__ float xs[BM];
    __shared__ float ys[BN];

    const int t   = threadIdx.x;
    const int bid = blockIdx.x;
    const int R0  = (bid >> 6) * BM;   // 64 col-tiles per row band
    const int C0  = (bid & 63) * BN;

    // ---- stage X/Y tiles: global f32 (coalesced 32B/lane) -> bf16 -> swizzled LDS ----
    {
        const float* gx = X + (size_t)R0 * DIM;
        const float* gy = Y + (size_t)C0 * DIM;
        char* lx = (char*)As;
        char* ly = (char*)Bs;
        #pragma unroll
        for (int i = 0; i < 8; ++i) {
            int q = i * 256 + t;          // 32B (8-float) chunk id, globally linear
            int r = q >> 4;               // tile row
            int c = q & 15;               // 16B bf16 chunk within row
            const f32x4* gpx = (const f32x4*)(gx + q * 8);
            f32x4 a0 = gpx[0], a1 = gpx[1];
            const f32x4* gpy = (const f32x4*)(gy + q * 8);
            f32x4 b0 = gpy[0], b1 = gpy[1];
            short8 pa, pb;
            pa[0]=f2bf(a0[0]); pa[1]=f2bf(a0[1]); pa[2]=f2bf(a0[2]); pa[3]=f2bf(a0[3]);
            pa[4]=f2bf(a1[0]); pa[5]=f2bf(a1[1]); pa[6]=f2bf(a1[2]); pa[7]=f2bf(a1[3]);
            pb[0]=f2bf(b0[0]); pb[1]=f2bf(b0[1]); pb[2]=f2bf(b0[2]); pb[3]=f2bf(b0[3]);
            pb[4]=f2bf(b1[0]); pb[5]=f2bf(b1[1]); pb[6]=f2bf(b1[2]); pb[7]=f2bf(b1[3]);
            int off = r * 256 + ((c * 16) ^ ((r & 7) << 4));
            *(short8*)(lx + off) = pa;
            *(short8*)(ly + off) = pb;
        }
    }

    // ---- exact f32 row norms (re-read global; L2-hot since just staged) ----
    {
        const float* row = (t < 128) ? (X + (size_t)(R0 + t) * DIM)
                                     : (Y + (size_t)(C0 + (t - 128)) * DIM);
        float s = 0.f;
        #pragma unroll
        for (int i = 0; i < DIM; i += 4) {
            f32x4 v = *(const f32x4*)(row + i);
            s += v[0]*v[0] + v[1]*v[1] + v[2]*v[2] + v[3]*v[3];
        }
        if (t < 128) xs[t] = s; else ys[t - 128] = s;
    }

    __syncthreads();

    // ---- MFMA: 4 waves, each a 64x64 sub-tile = 4x4 frags of 16x16, K=128 in 4 steps ----
    const int wid = t >> 6, lane = t & 63;
    const int wr = wid >> 1, wc = wid & 1;
    const int lg = lane >> 4, lr = lane & 15;

    f32x4 acc[4][4];
    #pragma unroll
    for (int i = 0; i < 4; ++i)
        #pragma unroll
        for (int j = 0; j < 4; ++j)
            acc[i][j] = (f32x4){0.f, 0.f, 0.f, 0.f};

    const char* lA = (const char*)As;
    const char* lB = (const char*)Bs;
    #pragma unroll
    for (int kk = 0; kk < 4; ++kk) {
        const int kb = kk * 64 + lg * 16;  // byte offset of this lane-group's 8 k-elems
        short8 a[4], b[4];
        #pragma unroll
        for (int i = 0; i < 4; ++i) {
            int ar = wr * 64 + i * 16 + lr;
            a[i] = *(const short8*)(lA + ar * 256 + (kb ^ ((ar & 7) << 4)));
            int br = wc * 64 + i * 16 + lr;
            b[i] = *(const short8*)(lB + br * 256 + (kb ^ ((br & 7) << 4)));
        }
        #pragma unroll
        for (int i = 0; i < 4; ++i)
            #pragma unroll
            for (int j = 0; j < 4; ++j)
                acc[i][j] = __builtin_amdgcn_mfma_f32_16x16x32_bf16(a[i], b[j], acc[i][j], 0, 0, 0);
    }

    // ---- fused epilogue: out = xs[row] + ys[col] - 2*cross ----
    // C/D layout (verified m89): col = lane&15, row = (lane>>4)*4 + reg
    #pragma unroll
    for (int i = 0; i < 4; ++i) {
        #pragma unroll
        for (int j = 0; j < 4; ++j) {
            const int row_l = wr * 64 + i * 16 + lg * 4;
            const int col_l = wc * 64 + j * 16 + lr;
            const float yv = ys[col_l];
            float* po = out + (size_t)(R0 + row_l) * NCOL + (C0 + col_l);
            #pragma unroll
            for (int r = 0; r < 4; ++r)
                po[(size_t)r * NCOL] = xs[row_l + r] + yv - 2.0f * acc[i][j][r];
        }
    }
}

extern "C" void kernel_launch(void* const* d_in, const int* in_sizes, int n_in,
                              void* d_out, int out_size, void* d_ws, size_t ws_size,
                              hipStream_t stream) {
    const float* x = (const float*)d_in[0];
    const float* y = (const float*)d_in[1];
    float* out = (float*)d_out;
    dim3 grid((NROW / BM) * (NCOL / BN));  // 64*64 = 4096 blocks
    dim3 block(256);
    dist_kernel<<<grid, block, 0, stream>>>(x, y, out);
}

// Round 2
// 89.489 us; speedup vs baseline: 1.1047x; 1.1047x over previous
//
#include <hip/hip_runtime.h>
#include <hip/hip_bf16.h>

// dist[n][m] = |x_n|^2 + |y_m|^2 - 2 x_n.y_m
// N=M=8192, D=128, f32 in/out. HBM-write-bound (256 MiB out, floor ~42us).
//
// prep_kernel: x,y f32 -> bf16 ONCE into d_ws, packed in MFMA-fragment order
//   (wave frag load == contiguous 1 KiB), + exact f32 row norms.
// dist_main:   no LDS, no barriers. 128x128 tile/block, 4 waves x 64x64.
//   Swapped-operand MFMA (mfma(b,a)) => lane's 4 acc regs = 4 consecutive
//   output COLUMNS => dwordx4 nontemporal stores.

typedef __attribute__((ext_vector_type(8))) short short8;
typedef __attribute__((ext_vector_type(4))) float f32x4;

#define NROW 8192
#define DIM  128

__device__ __forceinline__ short f2bf(float f) {
    unsigned u = __builtin_bit_cast(unsigned, f);
    unsigned r = u + 0x7FFFu + ((u >> 16) & 1u);
    return (short)(r >> 16);
}

// ---------------- prep: pack bf16 fragments + row norms ----------------
// Packed layout per matrix: [g=row/16][kk=k/32][lane=lg*16+lr] of 16B chunks,
// chunk(g,kk,lg,lr) = bf16 of M[g*16+lr][kk*32+lg*8 .. +8].
// => main-kernel frag load: 64 lanes read ((g*4+kk)*64+lane)*16B, contiguous.
__global__ __launch_bounds__(256)
void prep_kernel(const float* __restrict__ X, const float* __restrict__ Y,
                 unsigned short* __restrict__ Xp, unsigned short* __restrict__ Yp,
                 float* __restrict__ xn, float* __restrict__ yn)
{
    const int t   = blockIdx.x * 256 + threadIdx.x;   // 0 .. 262143
    const int sel = t >> 17;                          // 0 = x, 1 = y
    const int c   = t & 131071;                       // chunk id within matrix
    const int row = c >> 4;
    const int sub = c & 15;                           // 8-elem chunk within row

    const float* src = (sel ? Y : X) + (size_t)row * DIM + sub * 8;
    f32x4 v0 = ((const f32x4*)src)[0];
    f32x4 v1 = ((const f32x4*)src)[1];

    short8 p;
    p[0]=f2bf(v0[0]); p[1]=f2bf(v0[1]); p[2]=f2bf(v0[2]); p[3]=f2bf(v0[3]);
    p[4]=f2bf(v1[0]); p[5]=f2bf(v1[1]); p[6]=f2bf(v1[2]); p[7]=f2bf(v1[3]);

    // exact f32 partial norm, reduced over the 16 lanes sharing this row
    float part = v0[0]*v0[0] + v0[1]*v0[1] + v0[2]*v0[2] + v0[3]*v0[3]
               + v1[0]*v1[0] + v1[1]*v1[1] + v1[2]*v1[2] + v1[3]*v1[3];
    part += __shfl_xor(part, 1, 16);
    part += __shfl_xor(part, 2, 16);
    part += __shfl_xor(part, 4, 16);
    part += __shfl_xor(part, 8, 16);

    const int g = row >> 4, lr = row & 15, kk = sub >> 2, lg = sub & 3;
    unsigned short* dst = (sel ? Yp : Xp) + (size_t)(((g*4 + kk)*64) + lg*16 + lr) * 8;
    *(short8*)dst = p;
    if (sub == 0) (sel ? yn : xn)[row] = part;
}

// ---------------- main: 128x128 tile, no LDS, no barriers ----------------
__global__ __launch_bounds__(256, 3)
void dist_main(const unsigned short* __restrict__ Xp,
               const unsigned short* __restrict__ Yp,
               const float* __restrict__ xn, const float* __restrict__ yn,
               float* __restrict__ out)
{
    // XCD-bijective swizzle (4096 % 8 == 0): each XCD gets 8 contiguous
    // row bands -> per-XCD L2 working set = 0.25MB X-band + 2MB Y = resident.
    const int bid = blockIdx.x;
    const int wg  = (bid & 7) * 512 + (bid >> 3);
    const int R0  = (wg >> 6) * 128;
    const int C0  = (wg & 63) * 128;

    const int t    = threadIdx.x;
    const int wid  = t >> 6, lane = t & 63;
    const int wr   = wid >> 1, wc = wid & 1;       // wave's 64x64 quadrant
    const int lr   = lane & 15, lg = lane >> 4;

    const short8* Ap = (const short8*)Xp;          // 16B chunks
    const short8* Bp = (const short8*)Yp;
    const int ga = (R0 >> 4) + wr * 4;             // + j
    const int gb = (C0 >> 4) + wc * 4;             // + i

    f32x4 acc[4][4];
    #pragma unroll
    for (int i = 0; i < 4; ++i)
        #pragma unroll
        for (int j = 0; j < 4; ++j)
            acc[i][j] = (f32x4){0.f, 0.f, 0.f, 0.f};

    #pragma unroll
    for (int kk = 0; kk < 4; ++kk) {
        short8 a[4], b[4];
        #pragma unroll
        for (int j = 0; j < 4; ++j)
            a[j] = Ap[(size_t)((ga + j) * 4 + kk) * 64 + lane];
        #pragma unroll
        for (int i = 0; i < 4; ++i)
            b[i] = Bp[(size_t)((gb + i) * 4 + kk) * 64 + lane];
        // D = mfma(B, A): D-row = y-index (out col), D-col = x-index (out row)
        #pragma unroll
        for (int i = 0; i < 4; ++i)
            #pragma unroll
            for (int j = 0; j < 4; ++j)
                acc[i][j] = __builtin_amdgcn_mfma_f32_16x16x32_bf16(b[i], a[j], acc[i][j], 0, 0, 0);
    }

    // Epilogue: lane holds out[n][m0..m0+3] per (i,j):
    //   n  = R0 + wr*64 + j*16 + lr          (D col = lane&15)
    //   m0 = C0 + wc*64 + i*16 + lg*4        (D row = (lane>>4)*4 + reg)
    float xnv[4];
    f32x4 ynv[4];
    #pragma unroll
    for (int j = 0; j < 4; ++j)
        xnv[j] = xn[R0 + wr * 64 + j * 16 + lr];
    #pragma unroll
    for (int i = 0; i < 4; ++i)
        ynv[i] = *(const f32x4*)(yn + C0 + wc * 64 + i * 16 + lg * 4);

    #pragma unroll
    for (int j = 0; j < 4; ++j) {
        const size_t roff = (size_t)(R0 + wr * 64 + j * 16 + lr) * NROW;
        #pragma unroll
        for (int i = 0; i < 4; ++i) {
            const int m0 = C0 + wc * 64 + i * 16 + lg * 4;
            f32x4 o;
            #pragma unroll
            for (int r = 0; r < 4; ++r)
                o[r] = xnv[j] + ynv[i][r] - 2.0f * acc[i][j][r];
            __builtin_nontemporal_store(o, (f32x4*)(out + roff + m0));
        }
    }
}

// ---------------- fallback (round-1 kernel) if ws_size too small ----------------
__global__ __launch_bounds__(256, 2)
void dist_fallback(const float* __restrict__ X, const float* __restrict__ Y,
                   float* __restrict__ out)
{
    __shared__ unsigned short As[128 * DIM];
    __shared__ unsigned short Bs[128 * DIM];
    __shared__ float xs[128];
    __shared__ float ys[128];

    const int t = threadIdx.x, bid = blockIdx.x;
    const int R0 = (bid >> 6) * 128, C0 = (bid & 63) * 128;
    {
        const float* gx = X + (size_t)R0 * DIM;
        const float* gy = Y + (size_t)C0 * DIM;
        char* lx = (char*)As; char* ly = (char*)Bs;
        #pragma unroll
        for (int i = 0; i < 8; ++i) {
            int q = i * 256 + t, r = q >> 4, c = q & 15;
            f32x4 a0 = ((const f32x4*)(gx + q*8))[0], a1 = ((const f32x4*)(gx + q*8))[1];
            f32x4 b0 = ((const f32x4*)(gy + q*8))[0], b1 = ((const f32x4*)(gy + q*8))[1];
            short8 pa, pb;
            #pragma unroll
            for (int e = 0; e < 4; ++e) { pa[e]=f2bf(a0[e]); pa[e+4]=f2bf(a1[e]); pb[e]=f2bf(b0[e]); pb[e+4]=f2bf(b1[e]); }
            int off = r * 256 + ((c * 16) ^ ((r & 7) << 4));
            *(short8*)(lx + off) = pa; *(short8*)(ly + off) = pb;
        }
    }
    {
        const float* row = (t < 128) ? (X + (size_t)(R0 + t) * DIM) : (Y + (size_t)(C0 + t - 128) * DIM);
        float s = 0.f;
        #pragma unroll
        for (int i = 0; i < DIM; i += 4) { f32x4 v = *(const f32x4*)(row + i); s += v[0]*v[0]+v[1]*v[1]+v[2]*v[2]+v[3]*v[3]; }
        if (t < 128) xs[t] = s; else ys[t - 128] = s;
    }
    __syncthreads();
    const int wid = t >> 6, lane = t & 63, wr = wid >> 1, wc = wid & 1, lg = lane >> 4, lrr = lane & 15;
    f32x4 acc[4][4];
    #pragma unroll
    for (int i = 0; i < 4; ++i) for (int j = 0; j < 4; ++j) acc[i][j] = (f32x4){0,0,0,0};
    const char* lA = (const char*)As; const char* lB = (const char*)Bs;
    #pragma unroll
    for (int kk = 0; kk < 4; ++kk) {
        const int kb = kk * 64 + lg * 16;
        short8 a[4], b[4];
        #pragma unroll
        for (int i = 0; i < 4; ++i) {
            int ar = wr*64 + i*16 + lrr; a[i] = *(const short8*)(lA + ar*256 + (kb ^ ((ar&7)<<4)));
            int br = wc*64 + i*16 + lrr; b[i] = *(const short8*)(lB + br*256 + (kb ^ ((br&7)<<4)));
        }
        #pragma unroll
        for (int i = 0; i < 4; ++i) for (int j = 0; j < 4; ++j)
            acc[i][j] = __builtin_amdgcn_mfma_f32_16x16x32_bf16(a[i], b[j], acc[i][j], 0, 0, 0);
    }
    #pragma unroll
    for (int i = 0; i < 4; ++i) for (int j = 0; j < 4; ++j) {
        const int row_l = wr*64 + i*16 + lg*4, col_l = wc*64 + j*16 + lrr;
        const float yv = ys[col_l];
        float* po = out + (size_t)(R0 + row_l) * NROW + (C0 + col_l);
        #pragma unroll
        for (int r = 0; r < 4; ++r) po[(size_t)r * NROW] = xs[row_l + r] + yv - 2.0f * acc[i][j][r];
    }
}

extern "C" void kernel_launch(void* const* d_in, const int* in_sizes, int n_in,
                              void* d_out, int out_size, void* d_ws, size_t ws_size,
                              hipStream_t stream) {
    const float* x = (const float*)d_in[0];
    const float* y = (const float*)d_in[1];
    float* out = (float*)d_out;

    const size_t XP_OFF = 0;
    const size_t YP_OFF = 2097152;            // 8192*128*2
    const size_t XN_OFF = 4194304;
    const size_t YN_OFF = 4194304 + 32768;
    const size_t NEED   = 4194304 + 65536;

    if (ws_size >= NEED) {
        char* w = (char*)d_ws;
        unsigned short* Xp = (unsigned short*)(w + XP_OFF);
        unsigned short* Yp = (unsigned short*)(w + YP_OFF);
        float* xnp = (float*)(w + XN_OFF);
        float* ynp = (float*)(w + YN_OFF);
        prep_kernel<<<1024, 256, 0, stream>>>(x, y, Xp, Yp, xnp, ynp);
        dist_main<<<4096, 256, 0, stream>>>(Xp, Yp, xnp, ynp, out);
    } else {
        dist_fallback<<<4096, 256, 0, stream>>>(x, y, out);
    }
}

// Round 3
// 64.344 us; speedup vs baseline: 1.5364x; 1.3908x over previous
//
#include <hip/hip_runtime.h>
#include <hip/hip_bf16.h>

// dist[n][m] = |x_n|^2 + |y_m|^2 - 2 x_n.y_m
// N=M=8192, D=128, f32 in/out. HBM-write-bound (256 MiB out, floor ~42us).
//
// prep_kernel: x,y f32 -> bf16 ONCE into d_ws, packed in MFMA-fragment order.
// dist_main:   128x128 tile/block, 4 waves x 64x64, no LDS in compute path.
//   Epilogue routes through a 32 KiB swizzled LDS half-tile transpose so NT
//   stores are 512B-contiguous full-cacheline runs (was 16 rows x 64B scatter).

typedef __attribute__((ext_vector_type(8))) short short8;
typedef __attribute__((ext_vector_type(4))) float f32x4;

#define NROW 8192
#define DIM  128

__device__ __forceinline__ short f2bf(float f) {
    unsigned u = __builtin_bit_cast(unsigned, f);
    unsigned r = u + 0x7FFFu + ((u >> 16) & 1u);
    return (short)(r >> 16);
}

// ---------------- prep: pack bf16 fragments + row norms ----------------
// chunk(g,kk,lg,lr) = bf16 of M[g*16+lr][kk*32+lg*8 .. +8]
// => main-kernel frag load: 64 lanes read ((g*4+kk)*64+lane)*16B, contiguous.
__global__ __launch_bounds__(256)
void prep_kernel(const float* __restrict__ X, const float* __restrict__ Y,
                 unsigned short* __restrict__ Xp, unsigned short* __restrict__ Yp,
                 float* __restrict__ xn, float* __restrict__ yn)
{
    const int t   = blockIdx.x * 256 + threadIdx.x;   // 0 .. 262143
    const int sel = t >> 17;                          // 0 = x, 1 = y
    const int c   = t & 131071;
    const int row = c >> 4;
    const int sub = c & 15;

    const float* src = (sel ? Y : X) + (size_t)row * DIM + sub * 8;
    f32x4 v0 = ((const f32x4*)src)[0];
    f32x4 v1 = ((const f32x4*)src)[1];

    short8 p;
    p[0]=f2bf(v0[0]); p[1]=f2bf(v0[1]); p[2]=f2bf(v0[2]); p[3]=f2bf(v0[3]);
    p[4]=f2bf(v1[0]); p[5]=f2bf(v1[1]); p[6]=f2bf(v1[2]); p[7]=f2bf(v1[3]);

    float part = v0[0]*v0[0] + v0[1]*v0[1] + v0[2]*v0[2] + v0[3]*v0[3]
               + v1[0]*v1[0] + v1[1]*v1[1] + v1[2]*v1[2] + v1[3]*v1[3];
    part += __shfl_xor(part, 1, 16);
    part += __shfl_xor(part, 2, 16);
    part += __shfl_xor(part, 4, 16);
    part += __shfl_xor(part, 8, 16);

    const int g = row >> 4, lr = row & 15, kk = sub >> 2, lg = sub & 3;
    unsigned short* dst = (sel ? Yp : Xp) + (size_t)(((g*4 + kk)*64) + lg*16 + lr) * 8;
    *(short8*)dst = p;
    if (sub == 0) (sel ? yn : xn)[row] = part;
}

// ---------------- main: 128x128 tile ----------------
__global__ __launch_bounds__(256, 3)
void dist_main(const unsigned short* __restrict__ Xp,
               const unsigned short* __restrict__ Yp,
               const float* __restrict__ xn, const float* __restrict__ yn,
               float* __restrict__ out)
{
    // 32 KiB half-tile staging for the contiguous-store epilogue.
    // Layout: 64 rows x 512B, 16B slot XOR-swizzled by (row&7).
    __shared__ char lds[64 * 512];

    const int bid = blockIdx.x;
    const int wg  = (bid & 7) * 512 + (bid >> 3);   // XCD-bijective swizzle
    const int R0  = (wg >> 6) * 128;
    const int C0  = (wg & 63) * 128;

    const int t    = threadIdx.x;
    const int wid  = t >> 6, lane = t & 63;
    const int wr   = wid >> 1, wc = wid & 1;        // wave's 64x64 quadrant
    const int lr   = lane & 15, lg = lane >> 4;

    const short8* Ap = (const short8*)Xp;
    const short8* Bp = (const short8*)Yp;
    const int ga = (R0 >> 4) + wr * 4;
    const int gb = (C0 >> 4) + wc * 4;

    f32x4 acc[4][4];
    #pragma unroll
    for (int i = 0; i < 4; ++i)
        #pragma unroll
        for (int j = 0; j < 4; ++j)
            acc[i][j] = (f32x4){0.f, 0.f, 0.f, 0.f};

    #pragma unroll
    for (int kk = 0; kk < 4; ++kk) {
        short8 a[4], b[4];
        #pragma unroll
        for (int j = 0; j < 4; ++j)
            a[j] = Ap[(size_t)((ga + j) * 4 + kk) * 64 + lane];
        #pragma unroll
        for (int i = 0; i < 4; ++i)
            b[i] = Bp[(size_t)((gb + i) * 4 + kk) * 64 + lane];
        // D = mfma(B, A): D-row = y-index (out col), D-col = x-index (out row)
        #pragma unroll
        for (int i = 0; i < 4; ++i)
            #pragma unroll
            for (int j = 0; j < 4; ++j)
                acc[i][j] = __builtin_amdgcn_mfma_f32_16x16x32_bf16(b[i], a[j], acc[i][j], 0, 0, 0);
    }

    // acc[i][j][r]:  n = R0 + wr*64 + j*16 + lr   (out row)
    //                m = C0 + wc*64 + i*16 + lg*4 + r  (out col, f32x4-contig)
    float xnv[4];
    f32x4 ynv[4];
    #pragma unroll
    for (int j = 0; j < 4; ++j)
        xnv[j] = xn[R0 + wr * 64 + j * 16 + lr];
    #pragma unroll
    for (int i = 0; i < 4; ++i)
        ynv[i] = *(const f32x4*)(yn + C0 + wc * 64 + i * 16 + lg * 4);

    // Two-pass epilogue: waves with wr==pass deposit their 64-row half into
    // LDS (fused math), then ALL threads stream it out as 512B-contiguous
    // full-line NT stores.
    #pragma unroll
    for (int pass = 0; pass < 2; ++pass) {
        if (wr == pass) {
            #pragma unroll
            for (int j = 0; j < 4; ++j) {
                const int row = j * 16 + lr;           // 0..63 local
                const int rs  = (row & 7) << 4;
                #pragma unroll
                for (int i = 0; i < 4; ++i) {
                    f32x4 o;
                    #pragma unroll
                    for (int r = 0; r < 4; ++r)
                        o[r] = xnv[j] + ynv[i][r] - 2.0f * acc[i][j][r];
                    const int slotb = (wc * 16 + i * 4 + lg) * 16;
                    *(f32x4*)(lds + row * 512 + (slotb ^ rs)) = o;
                }
            }
        }
        __syncthreads();
        const size_t gbase = (size_t)(R0 + pass * 64) * NROW + C0;
        #pragma unroll
        for (int q = 0; q < 8; ++q) {
            const int row   = q * 8 + (t >> 5);        // 0..63
            const int slotb = (t & 31) * 16;
            f32x4 v = *(const f32x4*)(lds + row * 512 + (slotb ^ ((row & 7) << 4)));
            __builtin_nontemporal_store(v, (f32x4*)(out + gbase + (size_t)row * NROW + (t & 31) * 4));
        }
        if (pass == 0) __syncthreads();
    }
}

// ---------------- fallback if ws_size too small ----------------
__global__ __launch_bounds__(256, 2)
void dist_fallback(const float* __restrict__ X, const float* __restrict__ Y,
                   float* __restrict__ out)
{
    __shared__ unsigned short As[128 * DIM];
    __shared__ unsigned short Bs[128 * DIM];
    __shared__ float xs[128];
    __shared__ float ys[128];

    const int t = threadIdx.x, bid = blockIdx.x;
    const int R0 = (bid >> 6) * 128, C0 = (bid & 63) * 128;
    {
        const float* gx = X + (size_t)R0 * DIM;
        const float* gy = Y + (size_t)C0 * DIM;
        char* lx = (char*)As; char* ly = (char*)Bs;
        #pragma unroll
        for (int i = 0; i < 8; ++i) {
            int q = i * 256 + t, r = q >> 4, c = q & 15;
            f32x4 a0 = ((const f32x4*)(gx + q*8))[0], a1 = ((const f32x4*)(gx + q*8))[1];
            f32x4 b0 = ((const f32x4*)(gy + q*8))[0], b1 = ((const f32x4*)(gy + q*8))[1];
            short8 pa, pb;
            #pragma unroll
            for (int e = 0; e < 4; ++e) { pa[e]=f2bf(a0[e]); pa[e+4]=f2bf(a1[e]); pb[e]=f2bf(b0[e]); pb[e+4]=f2bf(b1[e]); }
            int off = r * 256 + ((c * 16) ^ ((r & 7) << 4));
            *(short8*)(lx + off) = pa; *(short8*)(ly + off) = pb;
        }
    }
    {
        const float* row = (t < 128) ? (X + (size_t)(R0 + t) * DIM) : (Y + (size_t)(C0 + t - 128) * DIM);
        float s = 0.f;
        #pragma unroll
        for (int i = 0; i < DIM; i += 4) { f32x4 v = *(const f32x4*)(row + i); s += v[0]*v[0]+v[1]*v[1]+v[2]*v[2]+v[3]*v[3]; }
        if (t < 128) xs[t] = s; else ys[t - 128] = s;
    }
    __syncthreads();
    const int wid = t >> 6, lane = t & 63, wr = wid >> 1, wc = wid & 1, lg = lane >> 4, lrr = lane & 15;
    f32x4 acc[4][4];
    #pragma unroll
    for (int i = 0; i < 4; ++i) for (int j = 0; j < 4; ++j) acc[i][j] = (f32x4){0,0,0,0};
    const char* lA = (const char*)As; const char* lB = (const char*)Bs;
    #pragma unroll
    for (int kk = 0; kk < 4; ++kk) {
        const int kb = kk * 64 + lg * 16;
        short8 a[4], b[4];
        #pragma unroll
        for (int i = 0; i < 4; ++i) {
            int ar = wr*64 + i*16 + lrr; a[i] = *(const short8*)(lA + ar*256 + (kb ^ ((ar&7)<<4)));
            int br = wc*64 + i*16 + lrr; b[i] = *(const short8*)(lB + br*256 + (kb ^ ((br&7)<<4)));
        }
        #pragma unroll
        for (int i = 0; i < 4; ++i) for (int j = 0; j < 4; ++j)
            acc[i][j] = __builtin_amdgcn_mfma_f32_16x16x32_bf16(a[i], b[j], acc[i][j], 0, 0, 0);
    }
    #pragma unroll
    for (int i = 0; i < 4; ++i) for (int j = 0; j < 4; ++j) {
        const int row_l = wr*64 + i*16 + lg*4, col_l = wc*64 + j*16 + lrr;
        const float yv = ys[col_l];
        float* po = out + (size_t)(R0 + row_l) * NROW + (C0 + col_l);
        #pragma unroll
        for (int r = 0; r < 4; ++r) po[(size_t)r * NROW] = xs[row_l + r] + yv - 2.0f * acc[i][j][r];
    }
}

extern "C" void kernel_launch(void* const* d_in, const int* in_sizes, int n_in,
                              void* d_out, int out_size, void* d_ws, size_t ws_size,
                              hipStream_t stream) {
    const float* x = (const float*)d_in[0];
    const float* y = (const float*)d_in[1];
    float* out = (float*)d_out;

    const size_t XP_OFF = 0;
    const size_t YP_OFF = 2097152;            // 8192*128*2
    const size_t XN_OFF = 4194304;
    const size_t YN_OFF = 4194304 + 32768;
    const size_t NEED   = 4194304 + 65536;

    if (ws_size >= NEED) {
        char* w = (char*)d_ws;
        unsigned short* Xp = (unsigned short*)(w + XP_OFF);
        unsigned short* Yp = (unsigned short*)(w + YP_OFF);
        float* xnp = (float*)(w + XN_OFF);
        float* ynp = (float*)(w + YN_OFF);
        prep_kernel<<<1024, 256, 0, stream>>>(x, y, Xp, Yp, xnp, ynp);
        dist_main<<<4096, 256, 0, stream>>>(Xp, Yp, xnp, ynp, out);
    } else {
        dist_fallback<<<4096, 256, 0, stream>>>(x, y, out);
    }
}